// Round 1
// baseline (14083.301 us; speedup 1.0000x reference)
//
#include <hip/hip_runtime.h>
#include <math.h>

// Dims: B=128, T=256, D=512, F0=2048, F1=1024, R=B*T=32768
// ws layout (floats):
//  e0    @ 0          (16777216)  Y0 -> e0 -> later reused as gate0
//  e1    @ 16777216   (16777216)  Y1 -> e1 -> later reused as gate1
//  H0    @ 33554432   (257*65536) h0 history, slot 0 = zeros (h_{-1})
//  H1    @ 50397184   (257*65536)
//  cbuf  @ 67239936   (2*65536)   c state for both cells
//  psum  @ 67371008   (65536)
//  psq   @ 67436544   (65536)
//  mean  @ 67502080   (512)
//  scale @ 67502592   (512)
// total ~67.5M floats ~270 MB

__device__ __forceinline__ float sigmoidf_(float x){ return 1.0f/(1.0f+expf(-x)); }

// ---------------- generic 128x128 fp32 tiled GEMM: C = A @ W^T (+epilogues) ----
// A: M x K row-major, W: 512 x K row-major (N fixed = 512)
// MODE 0: out[rt(r)][n] = acc + bias[n], rt = (r%256)*128 + r/256   (emb, row remap)
// MODE 1: out[r][n] = sigmoid(acc + bias[n]) * other[r][n]          (gates)
// MODE 2: dual pair (A,W)+(A2,W2); out[(r%128)*256 + r/128][n] = tanh(acc+bias[n])
template<int MODE>
__global__ __launch_bounds__(256) void gemm128(
    const float* __restrict__ A, const float* __restrict__ W,
    const float* __restrict__ A2, const float* __restrict__ W2,
    const float* __restrict__ bias, const float* __restrict__ other,
    float* __restrict__ out, int M, int K)
{
  __shared__ float As[16][132];
  __shared__ float Ws[16][132];
  int bx = blockIdx.x;
  int ntile = bx & 3;
  int mtile = bx >> 2;
  int m0 = mtile*128, n0 = ntile*128;
  int tid = threadIdx.x;
  int tx = tid & 15, ty = tid >> 4;
  float acc[8][8];
  #pragma unroll
  for (int i=0;i<8;i++)
    #pragma unroll
    for (int j=0;j<8;j++) acc[i][j]=0.f;

  const int npair = (MODE==2)?2:1;
  for (int pair=0; pair<npair; ++pair){
    const float* __restrict__ Ap = pair ? A2 : A;
    const float* __restrict__ Wp = pair ? W2 : W;
    for (int k0=0;k0<K;k0+=16){
      #pragma unroll
      for (int p=0;p<2;p++){
        int f4 = tid*2+p;
        int row = f4>>2, kq = f4&3;
        float4 va = *(const float4*)&Ap[(size_t)(m0+row)*K + k0 + kq*4];
        As[kq*4+0][row]=va.x; As[kq*4+1][row]=va.y; As[kq*4+2][row]=va.z; As[kq*4+3][row]=va.w;
        float4 vw = *(const float4*)&Wp[(size_t)(n0+row)*K + k0 + kq*4];
        Ws[kq*4+0][row]=vw.x; Ws[kq*4+1][row]=vw.y; Ws[kq*4+2][row]=vw.z; Ws[kq*4+3][row]=vw.w;
      }
      __syncthreads();
      #pragma unroll
      for (int k=0;k<16;k++){
        float4 a0 = *(const float4*)&As[k][ty*8];
        float4 a1 = *(const float4*)&As[k][ty*8+4];
        float4 b0 = *(const float4*)&Ws[k][tx*8];
        float4 b1 = *(const float4*)&Ws[k][tx*8+4];
        float av[8]={a0.x,a0.y,a0.z,a0.w,a1.x,a1.y,a1.z,a1.w};
        float bv[8]={b0.x,b0.y,b0.z,b0.w,b1.x,b1.y,b1.z,b1.w};
        #pragma unroll
        for (int i=0;i<8;i++)
          #pragma unroll
          for (int j=0;j<8;j++) acc[i][j] = fmaf(av[i], bv[j], acc[i][j]);
      }
      __syncthreads();
    }
  }
  #pragma unroll
  for (int i=0;i<8;i++){
    int r = m0 + ty*8 + i;
    int nbase = n0 + tx*8;
    float vals[8];
    #pragma unroll
    for (int j=0;j<8;j++){
      float v = acc[i][j] + bias[nbase+j];
      if (MODE==1) v = sigmoidf_(v);
      if (MODE==2) v = tanhf(v);
      vals[j]=v;
    }
    if (MODE==1){
      const float* hp = other + (size_t)r*512 + nbase;
      #pragma unroll
      for (int j=0;j<8;j++) vals[j] *= hp[j];
    }
    size_t orow;
    if (MODE==0)      orow = (size_t)((r & 255)*128 + (r>>8));
    else if (MODE==1) orow = (size_t)r;
    else              orow = (size_t)((r & 127)*256 + (r>>7));
    float* op = out + orow*512 + nbase;
    float4 s0 = {vals[0],vals[1],vals[2],vals[3]};
    float4 s1 = {vals[4],vals[5],vals[6],vals[7]};
    *(float4*)op = s0;
    *(float4*)(op+4) = s1;
  }
}

// ---------------- BN stats & apply --------------------------------------------
__global__ __launch_bounds__(256) void bn_stats1(const float* __restrict__ Y,
                                                 float* __restrict__ psum,
                                                 float* __restrict__ psq)
{
  int blk = blockIdx.x;            // 128 blocks x 256 rows
  int tid = threadIdx.x;           // 256 threads x 2 cols
  const float* base = Y + (size_t)blk*256*512;
  float sx=0.f, sy=0.f, qx=0.f, qy=0.f;
  for (int r=0;r<256;r++){
    float2 v = *(const float2*)&base[(size_t)r*512 + tid*2];
    sx += v.x; sy += v.y; qx += v.x*v.x; qy += v.y*v.y;
  }
  psum[(size_t)blk*512 + tid*2]   = sx;
  psum[(size_t)blk*512 + tid*2+1] = sy;
  psq [(size_t)blk*512 + tid*2]   = qx;
  psq [(size_t)blk*512 + tid*2+1] = qy;
}

__global__ __launch_bounds__(512) void bn_stats2(const float* __restrict__ psum,
                                                 const float* __restrict__ psq,
                                                 float* __restrict__ mean,
                                                 float* __restrict__ scale)
{
  int c = threadIdx.x;
  float s=0.f, q=0.f;
  for (int b=0;b<128;b++){ s += psum[(size_t)b*512+c]; q += psq[(size_t)b*512+c]; }
  float mu = s * (1.0f/32768.0f);
  float var = q * (1.0f/32768.0f) - mu*mu;
  mean[c] = mu;
  scale[c] = rsqrtf(var + 1e-5f);
}

__global__ __launch_bounds__(256) void bn_apply(float* __restrict__ Y,
                                                const float* __restrict__ mean,
                                                const float* __restrict__ scale,
                                                const float* __restrict__ gamma,
                                                const float* __restrict__ beta)
{
  size_t idx = (size_t)blockIdx.x*256 + threadIdx.x;   // one float4 each
  float4 v = *(float4*)&Y[idx*4];
  int c = (int)((idx*4) & 511);
  float r[4] = {v.x,v.y,v.z,v.w};
  #pragma unroll
  for (int u=0;u<4;u++){
    float t = (r[u]-mean[c+u])*scale[c+u]*gamma[c+u]+beta[c+u];
    r[u] = fmaxf(t, 0.f);
  }
  float4 o = {r[0],r[1],r[2],r[3]};
  *(float4*)&Y[idx*4] = o;
}

// ---------------- init h_{-1}=0, c=0 -------------------------------------------
__global__ __launch_bounds__(256) void init_state(float* __restrict__ H0,
                                                  float* __restrict__ H1,
                                                  float* __restrict__ cbuf)
{
  int idx = blockIdx.x*256 + threadIdx.x;  // 65536 threads
  H0[idx] = 0.f;
  H1[idx] = 0.f;
  cbuf[idx] = 0.f;
  cbuf[idx + 65536] = 0.f;
}

// ---------------- one LSTM timestep (both cells) --------------------------------
// 256 blocks: XCD-swizzled: x=bx&7 -> (cell=x>>2, d-quarter=x&3); s=bx>>3 ->
// (m-tile=s>>3 of 32 rows, d-tile=s&7 of 16 d's). Each block computes the 4 gate
// strips (i,f,g,o) for its 32 rows x 16 d's, K=1024 (e-part 512 + h-part 512),
// then the pointwise c/h update, writing h into H slot t+1.
__global__ __launch_bounds__(256) void scan_step(
    const float* __restrict__ e0, const float* __restrict__ e1,
    const float* __restrict__ w_ih0, const float* __restrict__ w_hh0,
    const float* __restrict__ b_ih0, const float* __restrict__ b_hh0,
    const float* __restrict__ w_ih1, const float* __restrict__ w_hh1,
    const float* __restrict__ b_ih1, const float* __restrict__ b_hh1,
    const float* __restrict__ mask,
    float* __restrict__ H0, float* __restrict__ H1,
    float* __restrict__ cbuf, int t)
{
  __shared__ float As[32][36];
  __shared__ float Ws[32][68];
  __shared__ float gbuf[4][32][17];

  int bx = blockIdx.x;
  int x = bx & 7, s = bx >> 3;
  int ci = x >> 2, dq = x & 3;
  int mt = s >> 3, dt = s & 7;
  int d0 = (dq*8 + dt)*16;
  int m0 = mt*32;

  const float* e   = ci ? e1 : e0;
  const float* wih = ci ? w_ih1 : w_ih0;
  const float* whh = ci ? w_hh1 : w_hh0;
  const float* bih = ci ? b_ih1 : b_ih0;
  const float* bhh = ci ? b_hh1 : b_hh0;
  float* H = ci ? H1 : H0;

  const float* eT    = e + ((size_t)t*128 + m0)*512;        // x_t rows
  const float* HprevT= H + ((size_t)t*128 + m0)*512;        // slot t = h_{t-1}

  int tid = threadIdx.x;
  int tx = tid & 63, ty = tid >> 6;

  float acc[8];
  #pragma unroll
  for (int i=0;i<8;i++) acc[i]=0.f;

  for (int kt=0; kt<32; ++kt){
    const float* Ap; const float* Wp; int k0;
    if (kt < 16){ Ap = eT;     Wp = wih; k0 = kt*32; }
    else        { Ap = HprevT; Wp = whh; k0 = (kt-16)*32; }
    // A tile: 32 rows x 32 k
    {
      int row = tid >> 3, kq = tid & 7;
      float4 v = *(const float4*)&Ap[(size_t)row*512 + k0 + kq*4];
      As[kq*4+0][row]=v.x; As[kq*4+1][row]=v.y; As[kq*4+2][row]=v.z; As[kq*4+3][row]=v.w;
    }
    // W tile: 64 gate-rows x 32 k
    #pragma unroll
    for (int p=0;p<2;p++){
      int f4 = tid + p*256;
      int row = f4 >> 3, kq = f4 & 7;
      int grow = (row>>4)*512 + d0 + (row & 15);
      float4 v = *(const float4*)&Wp[(size_t)grow*512 + k0 + kq*4];
      Ws[kq*4+0][row]=v.x; Ws[kq*4+1][row]=v.y; Ws[kq*4+2][row]=v.z; Ws[kq*4+3][row]=v.w;
    }
    __syncthreads();
    #pragma unroll
    for (int k=0;k<32;k++){
      float4 a0 = *(const float4*)&As[k][ty*8];
      float4 a1 = *(const float4*)&As[k][ty*8+4];
      float w = Ws[k][tx];
      acc[0] = fmaf(a0.x, w, acc[0]);
      acc[1] = fmaf(a0.y, w, acc[1]);
      acc[2] = fmaf(a0.z, w, acc[2]);
      acc[3] = fmaf(a0.w, w, acc[3]);
      acc[4] = fmaf(a1.x, w, acc[4]);
      acc[5] = fmaf(a1.y, w, acc[5]);
      acc[6] = fmaf(a1.z, w, acc[6]);
      acc[7] = fmaf(a1.w, w, acc[7]);
    }
    __syncthreads();
  }

  // stash gates (+combined bias) into LDS, grouped by gate type
  {
    int q = tx >> 4, dj = tx & 15;
    int grow = q*512 + d0 + dj;
    float bc = bih[grow] + bhh[grow];
    #pragma unroll
    for (int i=0;i<8;i++) gbuf[q][ty*8+i][dj] = acc[i] + bc;
  }
  __syncthreads();

  // pointwise LSTM update: 512 (b,d) items, 2 per thread
  #pragma unroll
  for (int p=0;p<2;p++){
    int it = tid + p*256;
    int m = it >> 4, dj = it & 15;
    float gi = gbuf[0][m][dj];
    float gf = gbuf[1][m][dj];
    float gg = gbuf[2][m][dj];
    float go = gbuf[3][m][dj];
    size_t cidx = (size_t)ci*65536 + (size_t)(m0+m)*512 + d0 + dj;
    float c = cbuf[cidx];
    float si = sigmoidf_(gi);
    float sf = sigmoidf_(gf);
    float so = sigmoidf_(go);
    float cn = sf*c + si*tanhf(gg);
    float h  = so*tanhf(cn);
    float mv = mask[(size_t)(m0+m)*256 + t];
    cn *= mv; h *= mv;
    cbuf[cidx] = cn;
    H[((size_t)(t+1)*128 + m0+m)*512 + d0 + dj] = h;
  }
}

// ---------------- launch ---------------------------------------------------------
extern "C" void kernel_launch(void* const* d_in, const int* in_sizes, int n_in,
                              void* d_out, int out_size, void* d_ws, size_t ws_size,
                              hipStream_t stream)
{
  const float* feat0  = (const float*)d_in[0];
  const float* feat1  = (const float*)d_in[1];
  const float* fmask  = (const float*)d_in[2];
  const float* w_emb0 = (const float*)d_in[3];
  const float* b_emb0 = (const float*)d_in[4];
  const float* gamma0 = (const float*)d_in[5];
  const float* beta0  = (const float*)d_in[6];
  const float* w_emb1 = (const float*)d_in[7];
  const float* b_emb1 = (const float*)d_in[8];
  const float* gamma1 = (const float*)d_in[9];
  const float* beta1  = (const float*)d_in[10];
  const float* w_ih0  = (const float*)d_in[11];
  const float* w_hh0  = (const float*)d_in[12];
  const float* b_ih0  = (const float*)d_in[13];
  const float* b_hh0  = (const float*)d_in[14];
  const float* w_ih1  = (const float*)d_in[15];
  const float* w_hh1  = (const float*)d_in[16];
  const float* b_ih1  = (const float*)d_in[17];
  const float* b_hh1  = (const float*)d_in[18];
  const float* wg0    = (const float*)d_in[19];
  const float* bg0    = (const float*)d_in[20];
  const float* wg1    = (const float*)d_in[21];
  const float* bg1    = (const float*)d_in[22];
  const float* wf1    = (const float*)d_in[23];
  const float* wf2    = (const float*)d_in[24];
  const float* bf     = (const float*)d_in[25];
  float* out = (float*)d_out;

  float* ws = (float*)d_ws;
  float* e0    = ws;
  float* e1    = ws + 16777216ULL;
  float* H0    = ws + 33554432ULL;
  float* H1    = ws + 50397184ULL;
  float* cbuf  = ws + 67239936ULL;
  float* psum  = ws + 67371008ULL;
  float* psq   = ws + 67436544ULL;
  float* meanb = ws + 67502080ULL;
  float* scaleb= ws + 67502592ULL;

  const int R = 32768;

  // embeddings (raw pre-BN), written t-major into e0/e1
  gemm128<0><<<dim3(1024), dim3(256), 0, stream>>>(feat0, w_emb0, nullptr, nullptr, b_emb0, nullptr, e0, R, 2048);
  gemm128<0><<<dim3(1024), dim3(256), 0, stream>>>(feat1, w_emb1, nullptr, nullptr, b_emb1, nullptr, e1, R, 1024);

  // BN + ReLU for e0
  bn_stats1<<<dim3(128), dim3(256), 0, stream>>>(e0, psum, psq);
  bn_stats2<<<dim3(1),   dim3(512), 0, stream>>>(psum, psq, meanb, scaleb);
  bn_apply <<<dim3(16384), dim3(256), 0, stream>>>(e0, meanb, scaleb, gamma0, beta0);
  // BN + ReLU for e1
  bn_stats1<<<dim3(128), dim3(256), 0, stream>>>(e1, psum, psq);
  bn_stats2<<<dim3(1),   dim3(512), 0, stream>>>(psum, psq, meanb, scaleb);
  bn_apply <<<dim3(16384), dim3(256), 0, stream>>>(e1, meanb, scaleb, gamma1, beta1);

  // scan
  init_state<<<dim3(256), dim3(256), 0, stream>>>(H0, H1, cbuf);
  for (int t=0; t<256; ++t){
    scan_step<<<dim3(256), dim3(256), 0, stream>>>(e0, e1,
        w_ih0, w_hh0, b_ih0, b_hh0,
        w_ih1, w_hh1, b_ih1, b_hh1,
        fmask, H0, H1, cbuf, t);
  }

  // gate0 = sigmoid(h1 @ wg0^T + bg0) * h0  -> e0 buffer
  gemm128<1><<<dim3(1024), dim3(256), 0, stream>>>(H1 + 65536, wg0, nullptr, nullptr, bg0, H0 + 65536, e0, R, 512);
  // gate1 = sigmoid(h0 @ wg1^T + bg1) * h1  -> e1 buffer
  gemm128<1><<<dim3(1024), dim3(256), 0, stream>>>(H0 + 65536, wg1, nullptr, nullptr, bg1, H1 + 65536, e1, R, 512);
  // out = tanh(g0 @ wf1^T + g1 @ wf2^T + bf), remapped to (B,T,D)
  gemm128<2><<<dim3(1024), dim3(256), 0, stream>>>(e0, wf1, e1, wf2, bf, nullptr, out, R, 512);
}